// Round 9
// baseline (370.833 us; speedup 1.0000x reference)
//
#include <hip/hip_runtime.h>
#include <math.h>

#define N_ROWS 32768
#define DIM    1024
#define NE     64
#define KTOP   8

// v10: expert-split waves, register-resident x, scalar-path w, no k-split.
//
// v5/v9 (148/161us) were latency-serialized (VALUBusy 34-38%, LDS+VALU both
// idle, conflicts 0, no spill): per-round staging VMEM sat on the critical
// path; LDS round-trip existed only to share x across the 8x8 tile.
// v0's (222us) real disease: each wave streamed a DIFFERENT 4KB w-window ->
// 32KB live through ~16KB K$ -> 100% scalar-cache miss, serialized.
// v10 keeps v0's skeleton (lane=row, x in regs, w via s_load) but splits
// EXPERTS across waves (wave wid owns experts wid*8..+8, full k):
//  - per 16-k chunk a wave pulls 512B scalar data (8x less than v0), and all
//    8 waves read the SAME 4KB window -> K$ hot. Raw s_barrier per chunk-pair
//    keeps windows aligned (no LDS in loop -> no memory semantics needed).
//  - x: per-lane 64B line per chunk (4x b128), even/odd double-buffer (no
//    copies), fully consumed -> no L1 thrash (v6 lesson).
//  - acc[8] only; NO k-split reduction: logits go straight to lg (stride 68:
//    16B-aligned b128 writes, minimal bank load).
// Register pressure ~60 VGPR -> spill impossible (v3/v4/v7 lesson).
// Epilogue = v0/v9-proven code (stride 68 instead of 65).

#define XLOAD(BUF, KC) do {                                              \
    *(float4*)((BUF) + 0)  = *(const float4*)(xrow + (KC) * 16 + 0);     \
    *(float4*)((BUF) + 4)  = *(const float4*)(xrow + (KC) * 16 + 4);     \
    *(float4*)((BUF) + 8)  = *(const float4*)(xrow + (KC) * 16 + 8);     \
    *(float4*)((BUF) + 12) = *(const float4*)(xrow + (KC) * 16 + 12);    \
} while (0)

#define CHUNK(BUF, KC) do {                                              \
    const float* wp_ = gwb + (KC) * 16;                                  \
    _Pragma("unroll")                                                    \
    for (int i_ = 0; i_ < 8; ++i_) {                                     \
        _Pragma("unroll")                                                \
        for (int kk_ = 0; kk_ < 16; ++kk_)                               \
            acc[i_] = fmaf((BUF)[kk_], wp_[i_ * DIM + kk_], acc[i_]);    \
    }                                                                    \
} while (0)

extern "C" __global__ void __launch_bounds__(512, 4)
moe_gate_kernel(const float* __restrict__ x, const float* __restrict__ gw,
                const float* __restrict__ nw, const float* __restrict__ noise,
                float* __restrict__ out0, float* __restrict__ out1,
                float* __restrict__ lossp,
                double* __restrict__ esum, int* __restrict__ ticket) {
    __shared__ __align__(16) float lg[64 * 68];   // logits, stride 68
    __shared__ float red[8 * 64];                 // epart reduction
    __shared__ int isLast;

    const int tid  = threadIdx.x;
    const int lane = tid & 63;
    const int wid  = __builtin_amdgcn_readfirstlane(tid >> 6);   // 0..7
    const int e0   = wid * 8;         // wave's 8 experts
    const int row0 = blockIdx.x * 64;

    float acc[8];
#pragma unroll
    for (int i = 0; i < 8; ++i) acc[i] = 0.f;

    const float* xrow = x  + (size_t)(row0 + lane) * DIM;   // per-lane (VMEM)
    const float* gwb  = gw + (size_t)e0 * DIM;              // uniform (SMEM)

    float xv[16], xn[16];
    XLOAD(xv, 0);

#pragma unroll 1
    for (int kc2 = 0; kc2 < 32; ++kc2) {          // two 16-k chunks per iter
        XLOAD(xn, 2 * kc2 + 1);                   // odd chunk in flight
        CHUNK(xv, 2 * kc2);
        if (kc2 < 31) XLOAD(xv, 2 * kc2 + 2);     // next even chunk in flight
        CHUNK(xn, 2 * kc2 + 1);
        __builtin_amdgcn_s_barrier();  // wave alignment only: keeps all 8
                                       // waves' s_loads in the same 4KB
                                       // K$ window (no LDS in this loop)
    }

    // ---- logits straight to LDS (no k-split reduction needed) ----
    // (lane*68 + e0)*4B is 16B-aligned (68*lane%4==0, e0%8==0).
    *(float4*)(&lg[lane * 68 + e0 + 0]) = make_float4(acc[0], acc[1], acc[2], acc[3]);
    *(float4*)(&lg[lane * 68 + e0 + 4]) = make_float4(acc[4], acc[5], acc[6], acc[7]);
    __syncthreads();

    // ---- epilogue: wave handles 8 rows, lane = expert (v0-proven code) ----
    const float nwl = nw[lane];
    float epart = 0.f;

#pragma unroll 1
    for (int i = 0; i < 8; ++i) {
        const int    lrow = wid * 8 + i;
        const size_t grow = (size_t)(row0 + lrow);
        const float  lgv  = lg[lrow * 68 + lane];

        // dense softmax over 64 experts (load-balance mean term)
        float m = lgv;
#pragma unroll
        for (int off = 32; off; off >>= 1) m = fmaxf(m, __shfl_xor(m, off));
        float p = __expf(lgv - m);
        float s = p;
#pragma unroll
        for (int off = 32; off; off >>= 1) s += __shfl_xor(s, off);
        epart += p / s;

        // noisy logits + iterative top-8 argmax (tie -> lower index)
        const float nz    = noise[grow * NE + lane];
        const float noisy = fmaf(nz, nwl, lgv);
        float cur  = noisy;
        bool  sel  = false;
        float mtop = 0.f;
        int   myid = 0;
#pragma unroll
        for (int j = 0; j < KTOP; ++j) {
            float v = cur; int id = lane;
#pragma unroll
            for (int off = 32; off; off >>= 1) {
                float ov = __shfl_xor(v, off);
                int   oi = __shfl_xor(id, off);
                if (ov > v || (ov == v && oi < id)) { v = ov; id = oi; }
            }
            if (j == 0) mtop = v;
            if (lane == id) { sel = true; cur = -INFINITY; }
            if (lane == j) myid = id;
        }

        float swv  = sel ? __expf(noisy - mtop) : 0.f;
        float ssum = swv;
#pragma unroll
        for (int off = 32; off; off >>= 1) ssum += __shfl_xor(ssum, off);

        out0[grow * NE + lane] = swv / ssum;                // coalesced 256 B/row
        if (lane < KTOP) out1[grow * KTOP + lane] = (float)myid;
    }

    // ---- load-balance sums: block partial -> device atomics ----
    __syncthreads();
    red[wid * 64 + lane] = epart;
    __syncthreads();
    if (tid < NE) {
        float t = 0.f;
#pragma unroll
        for (int w = 0; w < 8; ++w) t += red[w * 64 + tid];
        atomicAdd(&esum[tid], (double)t);
        __threadfence();
    }
    __syncthreads();
    if (tid == 0) {
        int t = atomicAdd(ticket, 1);
        isLast = (t == (int)gridDim.x - 1);
        __threadfence();
    }
    __syncthreads();

    // ---- last block computes the scalar loss (f64) ----
    if (isLast && tid < NE) {
        double v = atomicAdd(&esum[tid], 0.0);    // device-scope read
        double mean = v * (1.0 / 32768.0);
        double d  = mean - (1.0 / 64.0);
        double sq = d * d;
#pragma unroll
        for (int off = 32; off; off >>= 1) sq += __shfl_xor(sq, off);
        if (tid == 0) lossp[0] = (float)(sq * (1.0 / 64.0) * 0.01);
    }
}

extern "C" void kernel_launch(void* const* d_in, const int* in_sizes, int n_in,
                              void* d_out, int out_size, void* d_ws, size_t ws_size,
                              hipStream_t stream) {
    const float* x     = (const float*)d_in[0];   // [32768,1024]
    const float* gw    = (const float*)d_in[1];   // [64,1024]
    const float* nw    = (const float*)d_in[2];   // [64]
    const float* noise = (const float*)d_in[3];   // [32768,64]

    float* out0  = (float*)d_out;                       // [32768,64] gated weights
    float* out1  = out0 + (size_t)N_ROWS * NE;          // [32768,8] ids as f32
    float* lossp = out1 + (size_t)N_ROWS * KTOP;        // scalar loss

    double* esum   = (double*)d_ws;                     // [64]
    int*    ticket = (int*)((char*)d_ws + 512);

    hipMemsetAsync(d_ws, 0, 520, stream);
    moe_gate_kernel<<<N_ROWS / 64, 512, 0, stream>>>(x, gw, nw, noise,
                                                     out0, out1, lossp, esum, ticket);
}

// Round 10
// 291.258 us; speedup vs baseline: 1.2732x; 1.2732x over previous
//
#include <hip/hip_runtime.h>
#include <math.h>

#define N_ROWS 32768
#define DIM    1024
#define NE     64
#define KTOP   8

// v11 = v5 (148us, best) + cross-round VMEM prefetch done right.
//
// Evidence base: v0/v10 (222/228us) scalar-path w = latency-structural dead
// end. v5 (148us): 8x8 tile, both operands LDS, no barriers, no spill;
// decomposition FMA 27us + LDS ~45us floor -> ~100us EXPOSED VMEM latency
// (lockstep convoy: every wave issues staging loads then immediately
// ds_writes them -> ~900cyc HBM x-gather on the critical path each round).
// v7 (190us) proved prefetch+q-pipeline together spill (176 live regs);
// v9 (161us) proved the q-pipeline alone is a LOSS and stride-68 kills all
// reduction conflicts. So: keep v5's plain unroll-1 q-loop, add ONLY the
// prefetch (acc64 + px/pw16 + xf/wf16 + addr ~= 106 < 128 cap).
//
// Round r: [load px/pw for r+1 (clamped idx, unconditional, branch-free)]
//          [sched_barrier(0): pins loads above the q-loop, stops LLVM
//           sinking them to their use]
//          [8x (4 ds_read_b128 + 64 FMA) ~= 1024 cyc -- latency cover]
//          [ds_write px/pw (compiler inserts the vmcnt wait here; data
//           arrived long ago)] -- single buffer: same-wave DS ordering makes
//          the overwrite-after-read safe; still zero barriers in main loop.
// rnd=15 writes back its own (identical) data -- harmless, keeps body
// branch-free. Reduction (stride-68) + epilogue = v9 verbatim (passed).

extern "C" __global__ void __launch_bounds__(512, 4)
moe_gate_kernel(const float* __restrict__ x, const float* __restrict__ gw,
                const float* __restrict__ nw, const float* __restrict__ noise,
                float* __restrict__ out0, float* __restrict__ out1,
                float* __restrict__ lossp,
                double* __restrict__ esum, int* __restrict__ ticket) {
    __shared__ __align__(16) float smem[8512];   // 34,048 B
    __shared__ int isLast;
    float* xt  = smem;          // [8 wid][8 q][64 row] private slices
    float* wt  = smem + 4096;   // [8 wid][8 q][64 e]   private slices
    float* red = smem;          // overlay: [8 wid][544] = wid*544 + rr*68 + e
    float* lg  = smem + 4352;   // overlay: logits [64*65]

    const int tid  = threadIdx.x;
    const int lane = tid & 63;
    const int wid  = __builtin_amdgcn_readfirstlane(tid >> 6);   // 0..7
    const int er   = lane >> 3;       // expert-group: experts er*8 + n
    const int rr   = lane & 7;        // row-group:    rows    rr*8 + m
    const int er8  = er * 8;
    const int rr8  = rr * 8;
    const int row0 = blockIdx.x * 64;
    const int kwb  = wid * 128;       // wave's contiguous k-range

    float acc[8][8];
#pragma unroll
    for (int m = 0; m < 8; ++m)
#pragma unroll
        for (int n = 0; n < 8; ++n) acc[m][n] = 0.f;

    // staging: thread (wid,lane) loads x[row0+lane][kwb+rnd*8..+8] and
    // gw[lane][kwb+rnd*8..+8]; writes k-major into its wave's private slices.
    const float* gx   = x  + (size_t)(row0 + lane) * DIM + kwb;
    const float* gwp  = gw + (size_t)lane * DIM + kwb;
    float*       ws_x = xt + wid * 512 + lane;     // + q*64
    float*       ws_w = wt + wid * 512 + lane;
    const float* rd_x = xt + wid * 512 + rr8;      // + q*64
    const float* rd_w = wt + wid * 512 + er8;

    float px[8], pw[8];
    // prologue: round 0 load + stage (latency exposed once)
    *(float4*)(px + 0) = *(const float4*)(gx + 0);
    *(float4*)(px + 4) = *(const float4*)(gx + 4);
    *(float4*)(pw + 0) = *(const float4*)(gwp + 0);
    *(float4*)(pw + 4) = *(const float4*)(gwp + 4);
#pragma unroll
    for (int q = 0; q < 8; ++q) {
        ws_x[q * 64] = px[q];
        ws_w[q * 64] = pw[q];
    }

#pragma unroll 1
    for (int rnd = 0; rnd < 16; ++rnd) {
        // ---- issue round rnd+1's loads NOW (branch-free clamped index) ----
        const int nxt = (rnd < 15) ? (rnd + 1) * 8 : 15 * 8;   // uniform select
        *(float4*)(px + 0) = *(const float4*)(gx  + nxt + 0);
        *(float4*)(px + 4) = *(const float4*)(gx  + nxt + 4);
        *(float4*)(pw + 0) = *(const float4*)(gwp + nxt + 0);
        *(float4*)(pw + 4) = *(const float4*)(gwp + nxt + 4);
        __builtin_amdgcn_sched_barrier(0);   // pin loads above the q-loop

        // ---- v5's plain q-loop (unroll 1): ~1024 cyc of FMA cover ----
#pragma unroll 1
        for (int q = 0; q < 8; ++q) {
            float xf[8], wf[8];
            *(float4*)(xf + 0) = *(const float4*)(rd_x + q * 64 + 0);
            *(float4*)(xf + 4) = *(const float4*)(rd_x + q * 64 + 4);
            *(float4*)(wf + 0) = *(const float4*)(rd_w + q * 64 + 0);
            *(float4*)(wf + 4) = *(const float4*)(rd_w + q * 64 + 4);
#pragma unroll
            for (int m = 0; m < 8; ++m)
#pragma unroll
                for (int n = 0; n < 8; ++n)
                    acc[m][n] = fmaf(xf[m], wf[n], acc[m][n]);
        }

        // ---- stage rnd+1 (vmcnt wait lands here; latency already covered;
        //      same-wave DS order makes single-buffer overwrite safe) ----
#pragma unroll
        for (int q = 0; q < 8; ++q) {
            ws_x[q * 64] = px[q];
            ws_w[q * 64] = pw[q];
        }
    }

    // ---- k-split reduction over the 8 waves (stride-68, v9-verified) ----
    __syncthreads();                  // all waves done with xt/wt
#pragma unroll
    for (int s = 0; s < 8; ++s) {     // row = rr*8 + s
        float4 v0 = make_float4(acc[s][0], acc[s][1], acc[s][2], acc[s][3]);
        float4 v1 = make_float4(acc[s][4], acc[s][5], acc[s][6], acc[s][7]);
        *(float4*)(red + wid * 544 + rr * 68 + er8 + 0) = v0;
        *(float4*)(red + wid * 544 + rr * 68 + er8 + 4) = v1;
        __syncthreads();
        {
            const int r2 = tid >> 6, e = tid & 63;
            float t = 0.f;
#pragma unroll
            for (int w = 0; w < 8; ++w) t += red[w * 544 + r2 * 68 + e];
            lg[(r2 * 8 + s) * 65 + e] = t;   // row r2*8+s, expert e
        }
        __syncthreads();
    }

    // ---- epilogue: wave handles 8 rows, lane = expert (v0-proven code) ----
    const float nwl = nw[lane];
    float epart = 0.f;

#pragma unroll 1
    for (int i = 0; i < 8; ++i) {
        const int    lrow = wid * 8 + i;
        const size_t grow = (size_t)(row0 + lrow);
        const float  lgv  = lg[lrow * 65 + lane];

        // dense softmax over 64 experts (load-balance mean term)
        float m = lgv;
#pragma unroll
        for (int off = 32; off; off >>= 1) m = fmaxf(m, __shfl_xor(m, off));
        float p = __expf(lgv - m);
        float s = p;
#pragma unroll
        for (int off = 32; off; off >>= 1) s += __shfl_xor(s, off);
        epart += p / s;

        // noisy logits + iterative top-8 argmax (tie -> lower index)
        const float nz    = noise[grow * NE + lane];
        const float noisy = fmaf(nz, nwl, lgv);
        float cur  = noisy;
        bool  sel  = false;
        float mtop = 0.f;
        int   myid = 0;
#pragma unroll
        for (int j = 0; j < KTOP; ++j) {
            float v = cur; int id = lane;
#pragma unroll
            for (int off = 32; off; off >>= 1) {
                float ov = __shfl_xor(v, off);
                int   oi = __shfl_xor(id, off);
                if (ov > v || (ov == v && oi < id)) { v = ov; id = oi; }
            }
            if (j == 0) mtop = v;
            if (lane == id) { sel = true; cur = -INFINITY; }
            if (lane == j) myid = id;
        }

        float swv  = sel ? __expf(noisy - mtop) : 0.f;
        float ssum = swv;
#pragma unroll
        for (int off = 32; off; off >>= 1) ssum += __shfl_xor(ssum, off);

        out0[grow * NE + lane] = swv / ssum;                // coalesced 256 B/row
        if (lane < KTOP) out1[grow * KTOP + lane] = (float)myid;
    }

    // ---- load-balance sums: block partial -> device atomics ----
    __syncthreads();                   // lg reads done; reuse red
    red[wid * 64 + lane] = epart;
    __syncthreads();
    if (tid < NE) {
        float t = 0.f;
#pragma unroll
        for (int w = 0; w < 8; ++w) t += red[w * 64 + tid];
        atomicAdd(&esum[tid], (double)t);
        __threadfence();
    }
    __syncthreads();
    if (tid == 0) {
        int t = atomicAdd(ticket, 1);
        isLast = (t == (int)gridDim.x - 1);
        __threadfence();
    }
    __syncthreads();

    // ---- last block computes the scalar loss (f64) ----
    if (isLast && tid < NE) {
        double v = atomicAdd(&esum[tid], 0.0);    // device-scope read
        double mean = v * (1.0 / 32768.0);
        double d  = mean - (1.0 / 64.0);
        double sq = d * d;
#pragma unroll
        for (int off = 32; off; off >>= 1) sq += __shfl_xor(sq, off);
        if (tid == 0) lossp[0] = (float)(sq * (1.0 / 64.0) * 0.01);
    }
}

extern "C" void kernel_launch(void* const* d_in, const int* in_sizes, int n_in,
                              void* d_out, int out_size, void* d_ws, size_t ws_size,
                              hipStream_t stream) {
    const float* x     = (const float*)d_in[0];   // [32768,1024]
    const float* gw    = (const float*)d_in[1];   // [64,1024]
    const float* nw    = (const float*)d_in[2];   // [64]
    const float* noise = (const float*)d_in[3];   // [32768,64]

    float* out0  = (float*)d_out;                       // [32768,64] gated weights
    float* out1  = out0 + (size_t)N_ROWS * NE;          // [32768,8] ids as f32
    float* lossp = out1 + (size_t)N_ROWS * KTOP;        // scalar loss

    double* esum   = (double*)d_ws;                     // [64]
    int*    ticket = (int*)((char*)d_ws + 512);

    hipMemsetAsync(d_ws, 0, 520, stream);
    moe_gate_kernel<<<N_ROWS / 64, 512, 0, stream>>>(x, gw, nw, noise,
                                                     out0, out1, lossp, esum, ticket);
}